// Round 4
// baseline (323.535 us; speedup 1.0000x reference)
//
#include <hip/hip_runtime.h>
#include <math.h>
#include <limits.h>

#define BATCH 256
#define VOCAB 128000
#define ROW_V4 (VOCAB / 4)          // 32000 float4 per row
#define PARTS 25
#define PART_V4 (ROW_V4 / PARTS)    // 1280 float4 per part
#define ATHREADS 256
#define PER_THREAD (PART_V4 / ATHREADS)  // 5 float4 per thread (uniform)
#define AWAVES (ATHREADS / 64)

typedef float vfloat4 __attribute__((ext_vector_type(4)));

// ws layout:
//   partials: [row][part][8] floats  = 256*25*8*4 = 204800 B
//   row_param: [row][2] floats (Msc, invS) at offset 204800
#define WS_PARTIALS_FLOATS (BATCH * PARTS * 8)

// ---------------------------------------------------------------- Kernel A
__global__ __launch_bounds__(ATHREADS) void partial_kernel(
    const float* __restrict__ logits,
    const float* __restrict__ temps,
    const float* __restrict__ noise,
    float* __restrict__ ws_partials)
{
    const int part = blockIdx.x;
    const int row  = blockIdx.y;
    const int tid  = threadIdx.x;
    const int wave = tid >> 6;
    const int lane = tid & 63;

    const float t     = temps[row];
    const float inv_t = (t == 0.0f) ? 1.0f : (1.0f / t);

    const vfloat4* lg4 = (const vfloat4*)(logits + (size_t)row * VOCAB);
    const vfloat4* nz4 = (const vfloat4*)(noise  + (size_t)row * VOCAB);
    const int base = part * PART_V4 + tid;

    // issue all 10 loads up-front: 10-deep MLP per wave
    vfloat4 x[PER_THREAD], u[PER_THREAD];
#pragma unroll
    for (int k = 0; k < PER_THREAD; ++k) x[k] = lg4[base + k * ATHREADS];
#pragma unroll
    for (int k = 0; k < PER_THREAD; ++k)
        u[k] = __builtin_nontemporal_load(&nz4[base + k * ATHREADS]);

    float mx = -INFINITY;
    float gv = -INFINITY; int gi = 0;
    float zv = -INFINITY; int zi = 0;
#pragma unroll
    for (int k = 0; k < PER_THREAD; ++k) {
#pragma unroll
        for (int j = 0; j < 4; ++j) {
            const int   idx = (base + k * ATHREADS) * 4 + j;  // row-relative index
            const float xx  = x[k][j];
            mx = fmaxf(mx, xx);
            if (xx > gv) { gv = xx; gi = idx; }    // idx increases with (k,j): '>' keeps first
            const float g = -__logf(-__logf(u[k][j]));
            const float z = __fmaf_rn(xx, inv_t, g);
            if (z > zv) { zv = z; zi = idx; }
        }
    }

    // wave reductions (64 lanes)
#pragma unroll
    for (int off = 32; off >= 1; off >>= 1) {
        mx = fmaxf(mx, __shfl_down(mx, off));
        float gv2 = __shfl_down(gv, off); int gi2 = __shfl_down(gi, off);
        if (gv2 > gv || (gv2 == gv && gi2 < gi)) { gv = gv2; gi = gi2; }
        float zv2 = __shfl_down(zv, off); int zi2 = __shfl_down(zi, off);
        if (zv2 > zv || (zv2 == zv && zi2 < zi)) { zv = zv2; zi = zi2; }
    }

    __shared__ float smx[AWAVES], sgv[AWAVES], szv[AWAVES];
    __shared__ int   sgi[AWAVES], szi[AWAVES];
    __shared__ float bMx;
    if (lane == 0) { smx[wave] = mx; sgv[wave] = gv; sgi[wave] = gi;
                     szv[wave] = zv; szi[wave] = zi; }
    __syncthreads();
    if (tid == 0) {
        float M = smx[0];
        for (int w = 1; w < AWAVES; ++w) M = fmaxf(M, smx[w]);
        bMx = M;
    }
    __syncthreads();
    const float Mx = bMx;

    // register-resident second sweep: local exp-sum, 4 independent accumulators
    float s0 = 0.f, s1 = 0.f, s2 = 0.f, s3 = 0.f;
#pragma unroll
    for (int k = 0; k < PER_THREAD; ++k) {
        s0 += __expf((x[k][0] - Mx) * inv_t);
        s1 += __expf((x[k][1] - Mx) * inv_t);
        s2 += __expf((x[k][2] - Mx) * inv_t);
        s3 += __expf((x[k][3] - Mx) * inv_t);
    }
    float ps = (s0 + s1) + (s2 + s3);
#pragma unroll
    for (int off = 32; off >= 1; off >>= 1) ps += __shfl_down(ps, off);

    __shared__ float ssum[AWAVES];
    if (lane == 0) ssum[wave] = ps;
    __syncthreads();
    if (tid == 0) {
        float S = 0.f;
        for (int w = 0; w < AWAVES; ++w) S += ssum[w];
        float GV = sgv[0]; int GI = sgi[0];
        float ZV = szv[0]; int ZI = szi[0];
        for (int w = 1; w < AWAVES; ++w) {
            if (sgv[w] > GV || (sgv[w] == GV && sgi[w] < GI)) { GV = sgv[w]; GI = sgi[w]; }
            if (szv[w] > ZV || (szv[w] == ZV && szi[w] < ZI)) { ZV = szv[w]; ZI = szi[w]; }
        }
        float* rec = ws_partials + ((size_t)row * PARTS + part) * 8;
        rec[0] = Mx; rec[1] = S; rec[2] = GV; ((int*)rec)[3] = GI;
        rec[4] = ZV; ((int*)rec)[5] = ZI;
    }
}

// ---------------------------------------------------------------- Kernel B
__global__ __launch_bounds__(64) void combine_kernel(
    const float* __restrict__ temps,
    const float* __restrict__ ws_partials,
    float* __restrict__ out_tokens,
    float* __restrict__ ws_row)
{
    const int row  = blockIdx.x;
    const int lane = threadIdx.x;

    const float t     = temps[row];
    const float inv_t = (t == 0.0f) ? 1.0f : (1.0f / t);

    float Mxp = -INFINITY, Sp = 0.f;
    float gv = -INFINITY; int gi = INT_MAX;
    float zv = -INFINITY; int zi = INT_MAX;
    if (lane < PARTS) {
        const float* rec = ws_partials + ((size_t)row * PARTS + lane) * 8;
        Mxp = rec[0]; Sp = rec[1];
        gv = rec[2]; gi = ((const int*)rec)[3];
        zv = rec[4]; zi = ((const int*)rec)[5];
    }
    // butterfly max so every lane has row max
    float Mx = Mxp;
#pragma unroll
    for (int off = 32; off >= 1; off >>= 1) Mx = fmaxf(Mx, __shfl_xor(Mx, off));

    float s = (lane < PARTS) ? Sp * __expf((Mxp - Mx) * inv_t) : 0.f;
#pragma unroll
    for (int off = 32; off >= 1; off >>= 1) {
        s += __shfl_xor(s, off);
        float gv2 = __shfl_xor(gv, off); int gi2 = __shfl_xor(gi, off);
        if (gv2 > gv || (gv2 == gv && gi2 < gi)) { gv = gv2; gi = gi2; }
        float zv2 = __shfl_xor(zv, off); int zi2 = __shfl_xor(zi, off);
        if (zv2 > zv || (zv2 == zv && zi2 < zi)) { zv = zv2; zi = zi2; }
    }
    if (lane == 0) {
        const int token = (t == 0.0f) ? gi : zi;
        out_tokens[row] = (float)token;
        ws_row[row * 2 + 0] = Mx * inv_t;   // Msc
        ws_row[row * 2 + 1] = 1.0f / s;     // invS
    }
}

// ---------------------------------------------------------------- Kernel C
__global__ __launch_bounds__(ATHREADS) void probs_kernel(
    const float* __restrict__ logits,
    const float* __restrict__ temps,
    const float* __restrict__ ws_row,
    float* __restrict__ out_probs)
{
    const int part = blockIdx.x;
    const int row  = blockIdx.y;
    const int tid  = threadIdx.x;

    const float t     = temps[row];
    const float inv_t = (t == 0.0f) ? 1.0f : (1.0f / t);
    const float Msc   = ws_row[row * 2 + 0];
    const float invS  = ws_row[row * 2 + 1];

    const vfloat4* lg4 = (const vfloat4*)(logits + (size_t)row * VOCAB);
    vfloat4*       pb4 = (vfloat4*)(out_probs + (size_t)row * VOCAB);
    const int base = part * PART_V4 + tid;

    vfloat4 x[PER_THREAD];
#pragma unroll
    for (int k = 0; k < PER_THREAD; ++k) x[k] = lg4[base + k * ATHREADS];
#pragma unroll
    for (int k = 0; k < PER_THREAD; ++k) {
        vfloat4 p;
#pragma unroll
        for (int j = 0; j < 4; ++j)
            p[j] = __expf(__fmaf_rn(x[k][j], inv_t, -Msc)) * invS;
        __builtin_nontemporal_store(p, &pb4[base + k * ATHREADS]);
    }
}

extern "C" void kernel_launch(void* const* d_in, const int* in_sizes, int n_in,
                              void* d_out, int out_size, void* d_ws, size_t ws_size,
                              hipStream_t stream) {
    const float* logits = (const float*)d_in[0];
    const float* temps  = (const float*)d_in[1];
    const float* noise  = (const float*)d_in[2];
    float* out = (float*)d_out;           // [tokens (256)] [probs (256*128000)]
    float* ws_partials = (float*)d_ws;
    float* ws_row      = ws_partials + WS_PARTIALS_FLOATS;

    partial_kernel<<<dim3(PARTS, BATCH), ATHREADS, 0, stream>>>(
        logits, temps, noise, ws_partials);
    combine_kernel<<<BATCH, 64, 0, stream>>>(
        temps, ws_partials, out, ws_row);
    probs_kernel<<<dim3(PARTS, BATCH), ATHREADS, 0, stream>>>(
        logits, temps, ws_row, out + BATCH);
}